// Round 1
// baseline (195.644 us; speedup 1.0000x reference)
//
#include <hip/hip_runtime.h>
#include <math.h>

#define BSZ 320
#define N2  640
#define DIM 128

// gamma = 1/0.07 as python double
#define GAM (1.0/0.07)

__device__ __forceinline__ double wave_reduce_sum(double v) {
    #pragma unroll
    for (int off = 32; off > 0; off >>= 1) v += __shfl_down(v, off, 64);
    return v;
}

// --- K1: normalize rows of z (f32 in) -> znT (f64, transposed: znT[k*640+row]) ---
__global__ void k_norm(const float* __restrict__ z, double* __restrict__ znT) {
    int row = blockIdx.x;          // 640
    int k   = threadIdx.x;         // 128
    double v  = (double)z[row * DIM + k];
    double sq = v * v;
    __shared__ double s2[2];
    double w = wave_reduce_sum(sq);
    int wave = k >> 6, lane = k & 63;
    if (lane == 0) s2[wave] = w;
    __syncthreads();
    double tot = s2[0] + s2[1];
    znT[k * N2 + row] = v / sqrt(tot);
}

// --- K2: K[i,j] = exp(-gamma*(2-2*dot)) for i<320, j<640.
// left half -> KK[i*320+j]; right half transposed -> KnT[(j-320)*320+i] ---
__global__ void k_gram(const double* __restrict__ znT, double* __restrict__ KK,
                       double* __restrict__ KnT) {
    int tid = blockIdx.x * 256 + threadIdx.x;   // 800 blocks
    if (tid >= BSZ * N2) return;
    int i = tid / N2, j = tid - i * N2;
    double s = 0.0;
    #pragma unroll 8
    for (int k = 0; k < DIM; k++) s = fma(znT[k * N2 + i], znT[k * N2 + j], s);
    double val = exp(-GAM * (2.0 - 2.0 * s));
    if (j < BSZ) KK[i * BSZ + j] = val;
    else         KnT[(j - BSZ) * BSZ + i] = val;
}

// --- K3: cs[j] = sum_i E[i,j] = colsum(KK)[j] - 1 ---
__global__ void k_colsum(const double* __restrict__ KK, double* __restrict__ cs) {
    int j  = blockIdx.x * 64 + threadIdx.x;  // grid 5, block (64,4)
    int ty = threadIdx.y;
    double s = 0.0;
    for (int i = ty; i < BSZ; i += 4) s += KK[i * BSZ + j];
    __shared__ double red[4][64];
    red[ty][threadIdx.x] = s;
    __syncthreads();
    if (ty == 0)
        cs[j] = red[0][threadIdx.x] + red[1][threadIdx.x] + red[2][threadIdx.x] +
                red[3][threadIdx.x] - 1.0;
}

// --- generic: dst[0] = sum of src[0..319] ---
__global__ void k_sum320(const double* __restrict__ src, double* __restrict__ dst) {
    int l = threadIdx.x;  // 64
    double s = 0.0;
    for (int j = l; j < BSZ; j += 64) s += src[j];
    s = wave_reduce_sum(s);
    if (l == 0) dst[0] = s;
}

// --- K4: B0 = M0inv - M0inv*E*M0inv, closed form (M0inv = a(I - cJ)) ---
__global__ void k_build(const double* __restrict__ KK, const double* __restrict__ cs,
                        const double* __restrict__ scal, double* __restrict__ B0) {
    int tid = blockIdx.x * 256 + threadIdx.x;  // 400 blocks
    if (tid >= BSZ * BSZ) return;
    int i = tid / BSZ, j = tid - i * BSZ;
    double kk  = KK[tid];
    double dij = (i == j) ? 1.0 : 0.0;
    double e   = kk - dij;
    const double a = 1.0 / 1.1;
    const double c = 1.0 / (320.0 + 1.1);
    double tot = scal[0];
    B0[tid] = a * (dij - c) - a * a * (e - c * (cs[i] + cs[j]) + c * c * tot);
}

// --- f64 320x320x320 matmul. AMODE: 0 plain A; 1 A=M built from KK; 2 A=KK w/ zero diag.
// EMODE: 0 C=A@B; 1 C=2*D - A@B ---
template <int AMODE, int EMODE>
__launch_bounds__(256)
__global__ void mm320(const double* __restrict__ A, const double* __restrict__ B,
                      double* __restrict__ C, const double* __restrict__ D) {
    __shared__ double As[32][33];
    __shared__ double Bs[32][33];
    const int tx = threadIdx.x, ty = threadIdx.y;  // 16x16
    const int lid = ty * 16 + tx;
    const int bi = blockIdx.y * 32, bj = blockIdx.x * 32;
    double a00 = 0, a01 = 0, a10 = 0, a11 = 0;
    for (int k0 = 0; k0 < BSZ; k0 += 32) {
        #pragma unroll
        for (int r = 0; r < 4; r++) {
            int e = lid + r * 256;
            int row = e >> 5, col = e & 31;
            int gi = bi + row, gk = k0 + col;
            double av = A[gi * BSZ + gk];
            if (AMODE == 1) av = 1.0 + av + ((gi == gk) ? 0.1 : 0.0);
            if (AMODE == 2) av = (gi == gk) ? 0.0 : av;
            As[row][col] = av;
            Bs[row][col] = B[(k0 + row) * BSZ + bj + col];
        }
        __syncthreads();
        #pragma unroll
        for (int kk = 0; kk < 32; kk++) {
            double x0 = As[ty * 2][kk], x1 = As[ty * 2 + 1][kk];
            double y0 = Bs[kk][tx * 2], y1 = Bs[kk][tx * 2 + 1];
            a00 = fma(x0, y0, a00); a01 = fma(x0, y1, a01);
            a10 = fma(x1, y0, a10); a11 = fma(x1, y1, a11);
        }
        __syncthreads();
    }
    int i0 = bi + ty * 2, j0 = bj + tx * 2;
    if (EMODE == 0) {
        C[i0 * BSZ + j0]           = a00;
        C[i0 * BSZ + j0 + 1]       = a01;
        C[(i0 + 1) * BSZ + j0]     = a10;
        C[(i0 + 1) * BSZ + j0 + 1] = a11;
    } else {
        C[i0 * BSZ + j0]           = 2.0 * D[i0 * BSZ + j0]           - a00;
        C[i0 * BSZ + j0 + 1]       = 2.0 * D[i0 * BSZ + j0 + 1]       - a01;
        C[(i0 + 1) * BSZ + j0]     = 2.0 * D[(i0 + 1) * BSZ + j0]     - a10;
        C[(i0 + 1) * BSZ + j0 + 1] = 2.0 * D[(i0 + 1) * BSZ + j0 + 1] - a11;
    }
}

// --- rowsums of Minv -> p ---
__global__ void k_rowsum(const double* __restrict__ Minv, double* __restrict__ p) {
    int i = blockIdx.x, l = threadIdx.x;  // 320 x 64
    double s = 0.0;
    for (int j = l; j < BSZ; j += 64) s += Minv[i * BSZ + j];
    s = wave_reduce_sum(s);
    if (l == 0) p[i] = s;
}

// --- per-t Woodbury + deletion scalars -> coefP/coefW/coefM, posterm ---
__global__ void k_coef(const double* __restrict__ V, const double* __restrict__ KK,
                       const double* __restrict__ p, const double* __restrict__ Minv,
                       const double* __restrict__ KnT, const double* __restrict__ scal,
                       double* __restrict__ coefP, double* __restrict__ coefW,
                       double* __restrict__ coefM, double* __restrict__ posterm) {
    int t = blockIdx.x, l = threadIdx.x;  // 320 x 64
    double sa = 0, sc1 = 0, sc2 = 0;
    for (int i = l; i < BSZ; i += 64) {
        double v  = V[t * BSZ + i];                       // V[t][i] = W[i][t]
        double kd = (i == t) ? 0.0 : KK[t * BSZ + i];     // KK_d0[t][i]
        sa += v; sc1 += kd * v; sc2 += kd * p[i];
    }
    sa  = wave_reduce_sum(sa);
    sc1 = wave_reduce_sum(sc1);
    sc2 = wave_reduce_sum(sc2);
    if (l == 0) {
        double b   = scal[1];
        double pt  = p[t];
        double Wtt = V[t * BSZ + t];
        double Mtt = Minv[t * BSZ + t];
        double s11 = 1.0 - sa, s12 = -b, s21 = -sc1, s22 = 1.0 - sc2;
        double det = s11 * s22 - s12 * s21;
        double r1 = 2.0 * b, r2 = 2.0 * sc2;
        double be1 = (s22 * r1 - s12 * r2) / det;
        double be2 = (s11 * r2 - s21 * r1) / det;
        double g1  = (s22 * pt - s12 * Wtt) / det;
        double g2  = (s11 * Wtt - s21 * pt) / det;
        double ytt = 2.0 * pt + be1 * Wtt + be2 * pt;
        double dt  = Mtt + g1 * Wtt + g2 * pt;
        double rho = ytt / dt;
        coefP[t] = 2.0 + be2 - rho * g2;
        coefW[t] = be1 - rho * g1;
        coefM[t] = -rho;
        posterm[t] = KnT[t * BSZ + t];   // K[t, bs+t]
    }
}

// --- final per-(t,i) pass: x, clip, accumulate 6 partial sums per t ---
__global__ void k_final(const double* __restrict__ V, const double* __restrict__ Minv,
                        const double* __restrict__ p, const double* __restrict__ KnT,
                        const double* __restrict__ coefP, const double* __restrict__ coefW,
                        const double* __restrict__ coefM, const double* __restrict__ posterm,
                        double* __restrict__ partials) {
    int t = blockIdx.x, i = threadIdx.x;  // 320 x 320 (5 waves)
    double cp = coefP[t], cw = coefW[t], cm = coefM[t];
    double s_neg = 0, s_al = 0, s_kn = 0, c0 = 0, c1v = 0, cpos = 0;
    if (i != t) {
        double x = cp * p[i] + cw * V[t * BSZ + i] + cm * Minv[t * BSZ + i];
        double alpha = fmin(fmax(x, 0.0), 1.0);
        double kn = KnT[t * BSZ + i];
        s_neg = alpha * kn; s_al = alpha; s_kn = kn;
        c0   = (x <= 0.0) ? 1.0 : 0.0;
        c1v  = (x >= 1.0) ? 1.0 : 0.0;
        cpos = (x > 0.0) ? 1.0 : 0.0;
    }
    s_neg = wave_reduce_sum(s_neg); s_al = wave_reduce_sum(s_al);
    s_kn  = wave_reduce_sum(s_kn);  c0   = wave_reduce_sum(c0);
    c1v   = wave_reduce_sum(c1v);   cpos = wave_reduce_sum(cpos);
    __shared__ double red[5][6];
    int wave = i >> 6, lane = i & 63;
    if (lane == 0) {
        red[wave][0] = s_neg; red[wave][1] = s_al; red[wave][2] = s_kn;
        red[wave][3] = c0;    red[wave][4] = c1v;  red[wave][5] = cpos;
    }
    __syncthreads();
    if (i == 0) {
        double a0 = 0, a1 = 0, a2 = 0, a3 = 0, a4 = 0, a5 = 0;
        for (int w = 0; w < 5; w++) {
            a0 += red[w][0]; a1 += red[w][1]; a2 += red[w][2];
            a3 += red[w][3]; a4 += red[w][4]; a5 += red[w][5];
        }
        partials[t * 6 + 0] = a0;
        partials[t * 6 + 1] = a1 * posterm[t];
        partials[t * 6 + 2] = a2;
        partials[t * 6 + 3] = a3;
        partials[t * 6 + 4] = a4;
        partials[t * 6 + 5] = a5;
    }
}

// --- reduce partials, write 6 f32 outputs ---
__global__ void k_out(const double* __restrict__ partials, const double* __restrict__ posterm,
                      float* __restrict__ out) {
    int l = threadIdx.x;  // 64
    double s0 = 0, s1 = 0, s2 = 0, s3 = 0, s4 = 0, s5 = 0, sp = 0;
    for (int t = l; t < BSZ; t += 64) {
        s0 += partials[t * 6 + 0]; s1 += partials[t * 6 + 1]; s2 += partials[t * 6 + 2];
        s3 += partials[t * 6 + 3]; s4 += partials[t * 6 + 4]; s5 += partials[t * 6 + 5];
        sp += posterm[t];
    }
    s0 = wave_reduce_sum(s0); s1 = wave_reduce_sum(s1); s2 = wave_reduce_sum(s2);
    s3 = wave_reduce_sum(s3); s4 = wave_reduce_sum(s4); s5 = wave_reduce_sum(s5);
    sp = wave_reduce_sum(sp);
    if (l == 0) {
        double neg = s0 / 320.0;
        double pos = s1 / 320.0;
        out[0] = (float)(neg - pos);                 // loss
        out[1] = (float)(sp / 320.0);                // pos_terms.mean()
        out[2] = (float)(s2 / (319.0 * 320.0));      // Kn.mean()
        out[3] = (float)(s4 / (s5 + 1e-10));         // sparsity
        out[4] = (float)(s3 / (320.0 * 319.0));      // num_zero
        out[5] = 0.0f;
    }
}

extern "C" void kernel_launch(void* const* d_in, const int* in_sizes, int n_in,
                              void* d_out, int out_size, void* d_ws, size_t ws_size,
                              hipStream_t stream) {
    const float* z = (const float*)d_in[0];
    float* out = (float*)d_out;
    double* ws = (double*)d_ws;

    // workspace layout (doubles); total ~5.6 MB
    double* znT = ws;                 // 81920
    double* KK  = znT + 81920;        // 102400
    double* KnT = KK + 102400;        // 102400
    double* Bb  = KnT + 102400;       // 102400  (B0 / NS ping)
    double* Tb  = Bb + 102400;        // 102400
    double* B2  = Tb + 102400;        // 102400  (NS pong)
    double* Vb  = B2 + 102400;        // 102400  (V = KKd0 @ Minv)
    double* p       = Vb + 102400;    // 320
    double* cs      = p + 320;        // 320
    double* coefP   = cs + 320;       // 320
    double* coefW   = coefP + 320;    // 320
    double* coefM   = coefW + 320;    // 320
    double* posterm = coefM + 320;    // 320
    double* scal    = posterm + 320;  // 16
    double* partials= scal + 16;      // 1920

    k_norm<<<dim3(640), dim3(128), 0, stream>>>(z, znT);
    k_gram<<<dim3(800), dim3(256), 0, stream>>>(znT, KK, KnT);
    k_colsum<<<dim3(5), dim3(64, 4), 0, stream>>>(KK, cs);
    k_sum320<<<dim3(1), dim3(64), 0, stream>>>(cs, scal + 0);          // tot(E)
    k_build<<<dim3(400), dim3(256), 0, stream>>>(KK, cs, scal, Bb);    // B0

    // Newton-Schulz x2: B <- 2B - B*(M*B); M built on the fly from KK
    mm320<1, 0><<<dim3(10, 10), dim3(16, 16), 0, stream>>>(KK, Bb, Tb, nullptr);
    mm320<0, 1><<<dim3(10, 10), dim3(16, 16), 0, stream>>>(Bb, Tb, B2, Bb);
    mm320<1, 0><<<dim3(10, 10), dim3(16, 16), 0, stream>>>(KK, B2, Tb, nullptr);
    mm320<0, 1><<<dim3(10, 10), dim3(16, 16), 0, stream>>>(B2, Tb, Bb, B2);  // Minv in Bb
    // V = KK_d0 @ Minv  (V[t][i] == W[i][t] by symmetry)
    mm320<2, 0><<<dim3(10, 10), dim3(16, 16), 0, stream>>>(KK, Bb, Vb, nullptr);

    k_rowsum<<<dim3(320), dim3(64), 0, stream>>>(Bb, p);               // p = Minv @ 1
    k_sum320<<<dim3(1), dim3(64), 0, stream>>>(p, scal + 1);           // b = 1'p
    k_coef<<<dim3(320), dim3(64), 0, stream>>>(Vb, KK, p, Bb, KnT, scal,
                                               coefP, coefW, coefM, posterm);
    k_final<<<dim3(320), dim3(320), 0, stream>>>(Vb, Bb, p, KnT,
                                                 coefP, coefW, coefM, posterm, partials);
    k_out<<<dim3(1), dim3(64), 0, stream>>>(partials, posterm, out);
}

// Round 2
// 31.431 us; speedup vs baseline: 6.2247x; 6.2247x over previous
//
#include <hip/hip_runtime.h>
#include <math.h>

#define BSZ 320
#define N2  640
#define DIM 128
#define GAM (1.0/0.07)

__device__ __forceinline__ double wave_reduce_sum(double v) {
    #pragma unroll
    for (int off = 32; off > 0; off >>= 1) v += __shfl_down(v, off, 64);
    return v;
}

// --- K1: normalize rows of z (f32 in) -> znT (k-major f32) + znR (row-major f32) ---
__global__ void k_norm(const float* __restrict__ z, float* __restrict__ znT,
                       float* __restrict__ znR) {
    int row = blockIdx.x;          // 640
    int k   = threadIdx.x;         // 128
    double v = (double)z[row * DIM + k];
    __shared__ double s2[2];
    double w = wave_reduce_sum(v * v);
    int wave = k >> 6, lane = k & 63;
    if (lane == 0) s2[wave] = w;
    __syncthreads();
    float zn = (float)(v / sqrt(s2[0] + s2[1]));
    znT[k * N2 + row] = zn;
    znR[row * DIM + k] = zn;
}

// --- K2: E rows (=KK with zero diag), KnT scatter, per-row stats rE, ssq ---
#define ROWS 2
__global__ void k_gram(const float* __restrict__ znT, const float* __restrict__ znR,
                       double* __restrict__ E, double* __restrict__ KnT,
                       double* __restrict__ rE, double* __restrict__ ssq) {
    __shared__ float zi[ROWS][DIM];
    __shared__ double sE[ROWS][10], sQ[ROWS][10];
    int j  = threadIdx.x;            // 640
    int i0 = blockIdx.x * ROWS;      // 160 blocks
    if (j < ROWS * DIM) {
        int r = j >> 7, k = j & 127;
        zi[r][k] = znR[(i0 + r) * DIM + k];
    }
    __syncthreads();
    float c0 = 0.f, c1 = 0.f;
    #pragma unroll 8
    for (int k = 0; k < DIM; k++) {
        float zj = znT[k * N2 + j];
        c0 = fmaf(zi[0][k], zj, c0);
        c1 = fmaf(zi[1][k], zj, c1);
    }
    double v0 = exp(-GAM * (2.0 - 2.0 * (double)c0));
    double v1 = exp(-GAM * (2.0 - 2.0 * (double)c1));
    double e0 = 0.0, e1 = 0.0;
    if (j < BSZ) {
        e0 = (j == i0    ) ? 0.0 : v0;
        e1 = (j == i0 + 1) ? 0.0 : v1;
        E[(i0    ) * BSZ + j] = e0;
        E[(i0 + 1) * BSZ + j] = e1;
    } else {
        KnT[(j - BSZ) * BSZ + i0    ] = v0;
        KnT[(j - BSZ) * BSZ + i0 + 1] = v1;
    }
    double q0 = e0 * e0, q1 = e1 * e1;
    e0 = wave_reduce_sum(e0); q0 = wave_reduce_sum(q0);
    e1 = wave_reduce_sum(e1); q1 = wave_reduce_sum(q1);
    int wave = j >> 6, lane = j & 63;
    if (lane == 0) { sE[0][wave] = e0; sQ[0][wave] = q0; sE[1][wave] = e1; sQ[1][wave] = q1; }
    __syncthreads();
    if (j < ROWS) {
        double se = 0.0, sq = 0.0;
        for (int w = 0; w < 10; w++) { se += sE[j][w]; sq += sQ[j][w]; }
        rE[i0 + j] = se; ssq[i0 + j] = sq;
    }
}

// --- K3: per-t Woodbury+deletion coefficients, all closed-form ---
__global__ void k_coef(const double* __restrict__ E, const double* __restrict__ rE,
                       const double* __restrict__ ssq, const double* __restrict__ KnT,
                       double* __restrict__ coefP, double* __restrict__ coefW,
                       double* __restrict__ coefM, double* __restrict__ posterm,
                       double* __restrict__ Sbuf) {
    int t = blockIdx.x, l = threadIdx.x;   // 320 x 64
    double Sp = 0.0, mvp = 0.0;
    for (int i = l; i < BSZ; i += 64) {
        double r = rE[i];
        Sp  += r;
        mvp += E[t * BSZ + i] * r;       // E[t][t]=0 stored, no special case
    }
    double S  = wave_reduce_sum(Sp);
    double mv = wave_reduce_sum(mvp);
    if (l == 0) {
        const double a = 1.0 / 1.1, c = 1.0 / 321.1;
        const double q = 1.0 - 320.0 * c;
        double rEt = rE[t], ssqt = ssq[t];
        double pt  = a * q - a * a * q * (rEt - c * S);            // (M^-1 1)[t]
        double b   = 320.0 * a * q - a * a * q * q * S;            // 1'M^-1 1
        double up  = a * q * rEt - a * a * q * (mv - c * S * rEt); // u'M^-1 1
        double sc1 = a * ssqt - a * c * rEt * rEt;                 // u'M^-1 u
        double Wtt = -a * c * rEt;                                 // (M^-1 u)[t]
        double Mtt = a * (1.0 - c) - a * a * (c * c * S - 2.0 * c * rEt);
        double s11 = 1.0 - up, s12 = -b, s21 = -sc1, s22 = 1.0 - up;
        double det = s11 * s22 - s12 * s21;
        double r1 = 2.0 * b, r2 = 2.0 * up;
        double be1 = (s22 * r1 - s12 * r2) / det;
        double be2 = (s11 * r2 - s21 * r1) / det;
        double g1  = (s22 * pt - s12 * Wtt) / det;
        double g2  = (s11 * Wtt - s21 * pt) / det;
        double ytt = 2.0 * pt + be1 * Wtt + be2 * pt;
        double dt  = Mtt + g1 * Wtt + g2 * pt;
        double rho = ytt / dt;
        coefP[t] = 2.0 + be2 - rho * g2;
        coefW[t] = be1 - rho * g1;
        coefM[t] = -rho;
        posterm[t] = KnT[t * BSZ + t];
        if (t == 0) Sbuf[0] = S;
    }
}

// --- K4: final per-(t,i) pass; p/V/Minv reconstructed closed-form ---
__global__ void k_final(const double* __restrict__ E, const double* __restrict__ rE,
                        const double* __restrict__ KnT, const double* __restrict__ Sbuf,
                        const double* __restrict__ coefP, const double* __restrict__ coefW,
                        const double* __restrict__ coefM, const double* __restrict__ posterm,
                        double* __restrict__ partials) {
    int t = blockIdx.x, i = threadIdx.x;   // 320 x 320
    const double a = 1.0 / 1.1, c = 1.0 / 321.1;
    const double q = 1.0 - 320.0 * c;
    double S = Sbuf[0];
    double cP = coefP[t], cW = coefW[t], cM = coefM[t], rEt = rE[t];
    double s_neg = 0, s_al = 0, s_kn = 0, c0 = 0, c1v = 0, cpos = 0;
    if (i != t) {
        double Eti = E[t * BSZ + i];
        double rEi = rE[i];
        double p_i = a * q - a * a * q * (rEi - c * S);
        double V   = a * Eti - a * c * rEt;
        double Mi  = -a * c - a * a * (Eti - c * (rEt + rEi) + c * c * S);
        double x = cP * p_i + cW * V + cM * Mi;
        double alpha = fmin(fmax(x, 0.0), 1.0);
        double kn = KnT[t * BSZ + i];
        s_neg = alpha * kn; s_al = alpha; s_kn = kn;
        c0   = (x <= 0.0) ? 1.0 : 0.0;
        c1v  = (x >= 1.0) ? 1.0 : 0.0;
        cpos = (x > 0.0) ? 1.0 : 0.0;
    }
    s_neg = wave_reduce_sum(s_neg); s_al = wave_reduce_sum(s_al);
    s_kn  = wave_reduce_sum(s_kn);  c0   = wave_reduce_sum(c0);
    c1v   = wave_reduce_sum(c1v);   cpos = wave_reduce_sum(cpos);
    __shared__ double red[5][6];
    int wave = i >> 6, lane = i & 63;
    if (lane == 0) {
        red[wave][0] = s_neg; red[wave][1] = s_al; red[wave][2] = s_kn;
        red[wave][3] = c0;    red[wave][4] = c1v;  red[wave][5] = cpos;
    }
    __syncthreads();
    if (i == 0) {
        double a0 = 0, a1 = 0, a2 = 0, a3 = 0, a4 = 0, a5 = 0;
        for (int w = 0; w < 5; w++) {
            a0 += red[w][0]; a1 += red[w][1]; a2 += red[w][2];
            a3 += red[w][3]; a4 += red[w][4]; a5 += red[w][5];
        }
        partials[t * 6 + 0] = a0;
        partials[t * 6 + 1] = a1 * posterm[t];
        partials[t * 6 + 2] = a2;
        partials[t * 6 + 3] = a3;
        partials[t * 6 + 4] = a4;
        partials[t * 6 + 5] = a5;
    }
}

// --- K5: reduce partials, write 6 f32 outputs ---
__global__ void k_out(const double* __restrict__ partials, const double* __restrict__ posterm,
                      float* __restrict__ out) {
    int l = threadIdx.x;  // 64
    double s0 = 0, s1 = 0, s2 = 0, s3 = 0, s4 = 0, s5 = 0, sp = 0;
    for (int t = l; t < BSZ; t += 64) {
        s0 += partials[t * 6 + 0]; s1 += partials[t * 6 + 1]; s2 += partials[t * 6 + 2];
        s3 += partials[t * 6 + 3]; s4 += partials[t * 6 + 4]; s5 += partials[t * 6 + 5];
        sp += posterm[t];
    }
    s0 = wave_reduce_sum(s0); s1 = wave_reduce_sum(s1); s2 = wave_reduce_sum(s2);
    s3 = wave_reduce_sum(s3); s4 = wave_reduce_sum(s4); s5 = wave_reduce_sum(s5);
    sp = wave_reduce_sum(sp);
    if (l == 0) {
        double neg = s0 / 320.0;
        double pos = s1 / 320.0;
        out[0] = (float)(neg - pos);
        out[1] = (float)(sp / 320.0);
        out[2] = (float)(s2 / (319.0 * 320.0));
        out[3] = (float)(s4 / (s5 + 1e-10));
        out[4] = (float)(s3 / (320.0 * 319.0));
        out[5] = 0.0f;
    }
}

extern "C" void kernel_launch(void* const* d_in, const int* in_sizes, int n_in,
                              void* d_out, int out_size, void* d_ws, size_t ws_size,
                              hipStream_t stream) {
    const float* z = (const float*)d_in[0];
    float* out = (float*)d_out;
    double* ws = (double*)d_ws;

    // f64 region
    double* E        = ws;                 // 102400
    double* KnT      = E + 102400;         // 102400
    double* rE       = KnT + 102400;       // 320
    double* ssq      = rE + 320;           // 320
    double* coefP    = ssq + 320;          // 320
    double* coefW    = coefP + 320;        // 320
    double* coefM    = coefW + 320;        // 320
    double* posterm  = coefM + 320;        // 320
    double* Sbuf     = posterm + 320;      // 8
    double* partials = Sbuf + 8;           // 1920
    // f32 region
    float* znT = (float*)(partials + 1920);   // 81920 floats
    float* znR = znT + 81920;                 // 81920 floats

    k_norm <<<dim3(640), dim3(128), 0, stream>>>(z, znT, znR);
    k_gram <<<dim3(BSZ / ROWS), dim3(640), 0, stream>>>(znT, znR, E, KnT, rE, ssq);
    k_coef <<<dim3(320), dim3(64), 0, stream>>>(E, rE, ssq, KnT, coefP, coefW, coefM,
                                                posterm, Sbuf);
    k_final<<<dim3(320), dim3(320), 0, stream>>>(E, rE, KnT, Sbuf, coefP, coefW, coefM,
                                                 posterm, partials);
    k_out  <<<dim3(1), dim3(64), 0, stream>>>(partials, posterm, out);
}